// Round 17
// baseline (622.122 us; speedup 1.0000x reference)
//
#include <hip/hip_runtime.h>

#define NN 200000
#define NE 600000
#define DD 128
#define DXX 3
#define DMM 256
#define NLVL 16

// ---- workspace byte offsets (total ~108.3 MB) ----
#define OFF_H      0LL                      // _Float16 h16[NN][128]     51,200,000
#define OFF_CSO    102400000LL              // int csr_off[NN+1]            800,016
#define OFF_DEG    103200016LL              // int deg[NN]                  800,000
#define OFF_CUR    104000016LL              // int cur[NN]                  800,000
#define OFF_CSRC   104800016LL              // int csr_pack[NE]           2,400,000
#define OFF_BSUM   107200016LL              // int bsum[256]                  1,024
#define OFF_NLIST  107201040LL              // int node_list[NN]            800,000
#define OFF_WCH    108001040LL              // _Float16 Wch[384][128]        98,304
#define OFF_GHC    108099344LL              // float ghc[384]                 1,536
#define OFF_MB     108100880LL              // float mb[384]                  1,536
#define OFF_W1H    108102416LL              // _Float16 W1h[256][128]        65,536
#define OFF_W2H    108167952LL              // _Float16 W2h[256][256]       131,072
#define OFF_CNT    108299024LL              // int counters[128]                512
#define WS_NEEDED  108299536LL

// cnt layout: [0..15] node_cnt  [32..48] node_start(17)  [66..81] node_cur

typedef float    f32x4 __attribute__((ext_vector_type(4)));
typedef _Float16 f16x8 __attribute__((ext_vector_type(8)));

__device__ __forceinline__ float sigm(float x){
  x = fminf(fmaxf(x, -30.f), 30.f);
  return 1.f/(1.f + __expf(-x));
}
__device__ __forceinline__ float tanh_(float x){
  x = fminf(fmaxf(x, -15.f), 15.f);
  float e = __expf(2.f*x);
  return (e - 1.f)/(e + 1.f);
}
__device__ __forceinline__ void acc8(float* acc, f16x8 v){
  for (int q = 0; q < 8; q++) acc[q] += (float)v[q];
}

// fused: init_h (fl==0 rows only) + node-level histogram + in-degree histogram
__global__ void k_pre(_Float16* h16, const int* fl, const int* dst,
                      const float* W_emd, const float* b_emd, int* cnt, int* deg){
  __shared__ int hn[NLVL];
  __shared__ _Float16 h0f[DD];
  if (threadIdx.x < NLVL) hn[threadIdx.x] = 0;
  if (threadIdx.x < DD) h0f[threadIdx.x] = (_Float16)(W_emd[threadIdx.x] + b_emd[threadIdx.x]);
  __syncthreads();
  const int tid = blockIdx.x*blockDim.x + threadIdx.x;
  const int stride = gridDim.x*blockDim.x;
  for (int i = tid; i < NN*16; i += stride){
    int row = i >> 4, ch = i & 15;
    if (fl[row] == 0)
      *(f16x8*)(h16 + (size_t)row*DD + ch*8) = *(const f16x8*)&h0f[ch*8];
  }
  for (int i = tid; i < NN; i += stride) atomicAdd(&hn[fl[i]], 1);
  for (int e = tid; e < NE; e += stride) atomicAdd(&deg[dst[e]], 1);
  __syncthreads();
  if (threadIdx.x < NLVL && hn[threadIdx.x])
    atomicAdd(&cnt[threadIdx.x], hn[threadIdx.x]);
}

__global__ void k_scan(int* cnt){
  if (threadIdx.x == 0){
    int s = 0;
    for (int l=0;l<NLVL;l++){ cnt[32+l] = s; s += cnt[l]; }
    cnt[48] = s;
    for (int l=0;l<NLVL;l++) cnt[66+l] = 0;
  }
}

// counting-sort fill of node_list (LDS hist + one global atomic per tile,level)
#define FB 1024
__global__ __launch_bounds__(256) void k_fill_n(const int* fl, int* cnt, int* node_list){
  __shared__ int hist[NLVL], base[NLVL];
  const int nt = (NN + FB - 1)/FB;
  for (int tile = blockIdx.x; tile < nt; tile += gridDim.x){
    const int i0 = tile*FB;
    if (threadIdx.x < NLVL) hist[threadIdx.x] = 0;
    __syncthreads();
    int lv[4], rk[4];
    #pragma unroll
    for (int j=0;j<4;j++){
      int i = i0 + threadIdx.x + j*256;
      if (i < NN){
        int l = fl[i];
        lv[j] = l;
        rk[j] = atomicAdd(&hist[l], 1);
      } else lv[j] = -1;
    }
    __syncthreads();
    if (threadIdx.x < NLVL)
      base[threadIdx.x] = atomicAdd(&cnt[66+threadIdx.x], hist[threadIdx.x]);
    __syncthreads();
    #pragma unroll
    for (int j=0;j<4;j++){
      if (lv[j] >= 0){
        int i = i0 + threadIdx.x + j*256;
        node_list[cnt[32+lv[j]] + base[lv[j]] + rk[j]] = i;
      }
    }
    __syncthreads();
  }
}

// 3-phase exclusive scan of deg -> csr_off
#define SCB 1024
__global__ __launch_bounds__(1024) void k_cscan1(const int* deg, int* cso, int* bsum){
  __shared__ int sh[SCB];
  const int b = blockIdx.x, t = threadIdx.x;
  const int i = b*SCB + t;
  int v = (i < NN) ? deg[i] : 0;
  sh[t] = v;
  __syncthreads();
  for (int ofs=1; ofs<SCB; ofs<<=1){
    int add = (t >= ofs) ? sh[t-ofs] : 0;
    __syncthreads();
    sh[t] += add;
    __syncthreads();
  }
  if (i < NN) cso[i] = sh[t] - v;   // exclusive
  if (t == SCB-1) bsum[b] = sh[t];
}

// fused: serial block-sum scan (1 thread) + weight precompute (all threads).
__global__ void k_cscan2_prep(int* bsum, int* cso, int nb,
                       const float* w_ih, const float* W_aggr, const float* b_aggr,
                       const float* w_hh, const float* W_emd, const float* b_emd,
                       const float* b_hh, const float* W1, const float* W2,
                       _Float16* Wch, float* ghc, float* mb,
                       _Float16* W1h, _Float16* W2h){
  if (blockIdx.x == 0 && threadIdx.x == 0){
    int run = 0;
    for (int b=0;b<nb;b++){ int tmp = bsum[b]; bsum[b] = run; run += tmp; }
    cso[NN] = run;
  }
  const int tid = blockIdx.x*blockDim.x + threadIdx.x;
  const int stride = gridDim.x*blockDim.x;
  for (int i = tid; i < 384*DD; i += stride){
    int r = i >> 7, k = i & (DD-1);
    float s = 0.f;
    for (int j=0;j<DD;j++) s += w_ih[r*(DD+DXX)+j]*W_aggr[j*DD+k];
    Wch[i] = (_Float16)s;          // [r][k] row-major
  }
  for (int i = tid; i < 384; i += stride){
    float s = 0.f, gg = 0.f;
    for (int j=0;j<DD;j++){
      s  += w_ih[i*(DD+DXX)+j]*b_aggr[j];
      gg += w_hh[i*DD+j]*(W_emd[j] + b_emd[j]);
    }
    mb[i]  = s;
    ghc[i] = gg + b_hh[i];
  }
  for (int i = tid; i < DMM*DD;  i += stride) W1h[i] = (_Float16)W1[i];
  for (int i = tid; i < DMM*DMM; i += stride) W2h[i] = (_Float16)W2[i];
}

__global__ __launch_bounds__(1024) void k_cscan3(int* cso, const int* bsum){
  const int i = blockIdx.x*SCB + threadIdx.x;
  if (i < NN) cso[i] += bsum[blockIdx.x];
}

// csr_pack[e] = src | (fl[src] << 24)
__global__ void k_csr_fill(const int* srcp, const int* dstp, const int* fl,
                           const int* cso, int* cur, int* csr_pack){
  for (int e = blockIdx.x*blockDim.x + threadIdx.x; e < NE; e += gridDim.x*blockDim.x){
    int d = dstp[e];
    int s = srcp[e];
    int p = atomicAdd(&cur[d], 1);
    csr_pack[cso[d] + p] = s | (fl[s] << 24);
  }
}

// ---- ONE level, fused gather + MFMA GRU; quad-batched pk loads
#define GT 32
__global__ __launch_bounds__(512, 4) void k_level_one(const int* cnt, const int l,
    const int* node_list, const int* cso, const int* csr_pack,
    const float* x, const _Float16* Wch, const float* ghc, const float* mb,
    const float* w_ih, const float* b_ih, const float* W_emd, const float* b_emd,
    _Float16* h16){
  const int n0 = cnt[32+l];
  const int na = cnt[32+l+1] - n0;
  const int tb = blockIdx.x * GT;
  if (tb >= na) return;

  __shared__ float s_l[GT][DD+4];
  __shared__ float x_l[GT][4];
  __shared__ float deg_l[GT];
  __shared__ int   vidx[GT], eoff[GT], ecnt[GT];
  __shared__ float h0s[DD];
  const int t    = threadIdx.x;
  const int w    = t >> 6;
  const int lane = t & 63;
  const int c0   = lane & 15;
  const int g    = lane >> 4;
  const int jo   = w*16 + c0;

  if (t < DD) h0s[t] = W_emd[t] + b_emd[t];
  if (t < GT){
    int row = tb + t;
    int v = (row < na) ? node_list[n0 + row] : -1;
    vidx[t] = v;
    int e0 = 0, e1 = 0;
    if (v >= 0){ e0 = cso[v]; e1 = cso[v+1]; }
    eoff[t] = e0; ecnt[t] = e1 - e0;
    deg_l[t] = (float)(e1 - e0);
    for (int kx=0; kx<DXX; kx++) x_l[t][kx] = (v >= 0) ? x[v*DXX + kx] : 0.f;
  }

  // weight frags + scalars issued BEFORE the gather so both latencies overlap
  f16x8 wcf[3][4];
  #pragma unroll
  for (int gate = 0; gate < 3; gate++){
    const _Float16* wp = Wch + (size_t)(gate*128 + jo)*DD + 8*g;
    #pragma unroll
    for (int ks = 0; ks < 4; ks++) wcf[gate][ks] = *(const f16x8*)(wp + ks*32);
  }
  float biv[3], mbv[3], ghcv[3], wxv[3][3];
  #pragma unroll
  for (int gate = 0; gate < 3; gate++){
    biv[gate]  = b_ih[gate*128 + jo];
    mbv[gate]  = mb[gate*128 + jo];
    ghcv[gate] = ghc[gate*128 + jo];
    #pragma unroll
    for (int kx = 0; kx < 3; kx++)
      wxv[gate][kx] = w_ih[(size_t)(gate*128 + jo)*(DD+DXX) + DD + kx];
  }
  const float h0v = W_emd[jo] + b_emd[jo];
  __syncthreads();

  // gather: 16 threads/row, dims [8*sub, 8*sub+8); quad-batched independent
  // pk loads then all eligible h loads in flight; f32 accumulate.
  {
    const int j = t >> 4, sub = t & 15;
    const int v = vidx[j];
    float acc[8] = {0,0,0,0,0,0,0,0};
    int nh0 = 0;
    if (v >= 0){
      const int e0 = eoff[j], n = ecnt[j];
      int i = 0;
      for (; i + 4 <= n; i += 4){
        int p0 = csr_pack[e0+i+0];
        int p1 = csr_pack[e0+i+1];
        int p2 = csr_pack[e0+i+2];
        int p3 = csr_pack[e0+i+3];
        int f0=p0>>24, f1=p1>>24, f2=p2>>24, f3=p3>>24;
        bool d0=(f0!=0)&(f0<l), d1=(f1!=0)&(f1<l), d2=(f2!=0)&(f2<l), d3=(f3!=0)&(f3<l);
        f16x8 v0, v1, v2, v3;
        if (d0) v0 = *(const f16x8*)(h16 + (size_t)(p0 & 0xFFFFFF)*DD + sub*8); else nh0++;
        if (d1) v1 = *(const f16x8*)(h16 + (size_t)(p1 & 0xFFFFFF)*DD + sub*8); else nh0++;
        if (d2) v2 = *(const f16x8*)(h16 + (size_t)(p2 & 0xFFFFFF)*DD + sub*8); else nh0++;
        if (d3) v3 = *(const f16x8*)(h16 + (size_t)(p3 & 0xFFFFFF)*DD + sub*8); else nh0++;
        if (d0) acc8(acc, v0);
        if (d1) acc8(acc, v1);
        if (d2) acc8(acc, v2);
        if (d3) acc8(acc, v3);
      }
      const int r = n - i;   // 0..3 tail: all pk loads first, then h loads
      if (r > 0){
        int p0 = csr_pack[e0+i];
        int p1 = (r > 1) ? csr_pack[e0+i+1] : 0;
        int p2 = (r > 2) ? csr_pack[e0+i+2] : 0;
        int f0=p0>>24, f1=p1>>24, f2=p2>>24;
        bool d0=(f0!=0)&(f0<l);
        bool d1=(r>1)&(f1!=0)&(f1<l);
        bool d2=(r>2)&(f2!=0)&(f2<l);
        f16x8 v0, v1, v2;
        if (d0) v0 = *(const f16x8*)(h16 + (size_t)(p0 & 0xFFFFFF)*DD + sub*8);
        if (d1) v1 = *(const f16x8*)(h16 + (size_t)(p1 & 0xFFFFFF)*DD + sub*8);
        if (d2) v2 = *(const f16x8*)(h16 + (size_t)(p2 & 0xFFFFFF)*DD + sub*8);
        nh0 += (d0?0:1) + ((r>1)?(d1?0:1):0) + ((r>2)?(d2?0:1):0);
        if (d0) acc8(acc, v0);
        if (d1) acc8(acc, v1);
        if (d2) acc8(acc, v2);
      }
      if (nh0){
        float nh = (float)nh0;
        for (int q=0;q<8;q++) acc[q] += nh*h0s[sub*8+q];
      }
    }
    *(float4*)&s_l[j][sub*8]     = make_float4(acc[0],acc[1],acc[2],acc[3]);
    *(float4*)&s_l[j][sub*8 + 4] = make_float4(acc[4],acc[5],acc[6],acc[7]);
  }
  __syncthreads();

  // MFMA GRU (gi only; gh == ghc const); 32 rows = 2 m-tiles
  #pragma unroll
  for (int m = 0; m < 2; m++){
    const int a_row = m*16 + c0;
    f16x8 as[4];
    #pragma unroll
    for (int ks = 0; ks < 4; ks++){
      const float* sp = &s_l[a_row][ks*32 + 8*g];
      f16x8 av;
      #pragma unroll
      for (int i2 = 0; i2 < 8; i2++) av[i2] = (_Float16)sp[i2];
      as[ks] = av;
    }
    f32x4 gi[3];
    #pragma unroll
    for (int gate = 0; gate < 3; gate++) gi[gate] = (f32x4){0.f,0.f,0.f,0.f};
    #pragma unroll
    for (int gate = 0; gate < 3; gate++)
      #pragma unroll
      for (int ks = 0; ks < 4; ks++)
        gi[gate] = __builtin_amdgcn_mfma_f32_16x16x32_f16(as[ks], wcf[gate][ks], gi[gate], 0, 0, 0);
    #pragma unroll
    for (int r = 0; r < 4; r++){
      const int node = m*16 + 4*g + r;
      const int v = vidx[node];
      if (v < 0) continue;
      const float dg = deg_l[node];
      float xr = 0.f, xz = 0.f, xn = 0.f;
      #pragma unroll
      for (int kx = 0; kx < 3; kx++){
        float xv = x_l[node][kx];
        xr = fmaf(wxv[0][kx], xv, xr);
        xz = fmaf(wxv[1][kx], xv, xz);
        xn = fmaf(wxv[2][kx], xv, xn);
      }
      float grv = gi[0][r] + biv[0] + dg*mbv[0] + xr + ghcv[0];
      float gzv = gi[1][r] + biv[1] + dg*mbv[1] + xz + ghcv[1];
      float rr = sigm(grv);
      float zz = sigm(gzv);
      float gnv = gi[2][r] + biv[2] + dg*mbv[2] + xn + rr*ghcv[2];
      float nv = tanh_(gnv);
      h16[(size_t)v*DD + jo] = (_Float16)((1.f - zz)*nv + zz*h0v);
    }
  }
}

// MFMA MLP, 16 waves/block; wave w owns cols [16w,16w+16) of both layers.
// __launch_bounds__(1024, 8): 8 waves/SIMD min => 2 resident 1024-thr blocks/CU
// (the r13-r15 (1024,2) asked for only 2 waves/SIMD — occupancy stuck at 41%).
// Register-prefetch staging: next tile's 16B/thread is loaded during compute.
__global__ __launch_bounds__(1024, 8) void k_mlp_pw(const _Float16* __restrict__ h16,
    const _Float16* __restrict__ W1h, const float* __restrict__ b1,
    const _Float16* __restrict__ W2h, const float* __restrict__ b2,
    const float* __restrict__ W3, const float* __restrict__ b3,
    float* __restrict__ out){
  __shared__ _Float16 hA[64*128];    // 16 KB swizzled (byte ^= (row&7)<<4, 256B rows)
  __shared__ _Float16 h1s[64*256];   // 32 KB swizzled (512B rows)
  __shared__ float red[16][64];      // 4 KB
  const int t    = threadIdx.x;
  const int w    = t >> 6;           // 0..15
  const int lane = t & 63;
  const int c    = lane & 15;
  const int g    = lane >> 4;
  const int col  = w*16 + c;         // this wave-lane's output column (both layers)

  f16x8 w1f[4], w2f[8];
  #pragma unroll
  for (int s = 0; s < 4; s++) w1f[s] = *(const f16x8*)(W1h + (size_t)col*DD  + s*32 + 8*g);
  #pragma unroll
  for (int s = 0; s < 8; s++) w2f[s] = *(const f16x8*)(W2h + (size_t)col*DMM + s*32 + 8*g);
  const float bb1 = b1[col], bb2 = b2[col], w3v = W3[col], b3s = b3[0];

  // swizzled LDS slot for this thread's stage chunk
  const int sbyte = t*16;
  const int srow  = sbyte >> 8;
  const int sswz  = sbyte ^ ((srow & 7) << 4);

  const int NT = NN/64;
  f16x8 stg = ((const f16x8*)(h16 + (size_t)blockIdx.x*64*DD))[t];  // first tile

  for (int tile = blockIdx.x; tile < NT; tile += gridDim.x){
    *(f16x8*)((char*)hA + sswz) = stg;
    __syncthreads();
    // issue next tile's stage load NOW; it completes during compute below
    {
      int nxt = tile + gridDim.x;
      if (nxt < NT) stg = ((const f16x8*)(h16 + (size_t)nxt*64*DD))[t];
    }

    // layer 1: acc[m] (16 rows x this lane's col), K=128
    f32x4 acc[4];
    #pragma unroll
    for (int m = 0; m < 4; m++){
      acc[m] = (f32x4){0.f,0.f,0.f,0.f};
      int row = m*16 + c;
      #pragma unroll
      for (int s = 0; s < 4; s++){
        int byte = row*256 + ((g*16 + s*64) ^ ((row & 7) << 4));
        f16x8 a1 = *(const f16x8*)((const char*)hA + byte);
        acc[m] = __builtin_amdgcn_mfma_f32_16x16x32_f16(a1, w1f[s], acc[m], 0, 0, 0);
      }
    }
    // h1 = relu(acc+b1) -> swizzled LDS (row 512B)
    #pragma unroll
    for (int m = 0; m < 4; m++)
      #pragma unroll
      for (int r = 0; r < 4; r++){
        int row = m*16 + 4*g + r;
        int off = (row*512 + col*2) ^ ((row & 7) << 4);
        *(_Float16*)((char*)h1s + off) = (_Float16)fmaxf(acc[m][r] + bb1, 0.f);
      }
    __syncthreads();

    // layer 2 + 3
    float p[4][4];
    #pragma unroll
    for (int m = 0; m < 4; m++){
      int row = m*16 + c;
      f16x8 a2[8];
      #pragma unroll
      for (int s = 0; s < 8; s++){
        int off = (row*512 + s*64 + g*16) ^ ((row & 7) << 4);
        a2[s] = *(const f16x8*)((const char*)h1s + off);
      }
      f32x4 acc2 = (f32x4){0.f,0.f,0.f,0.f};
      #pragma unroll
      for (int s = 0; s < 8; s++)
        acc2 = __builtin_amdgcn_mfma_f32_16x16x32_f16(a2[s], w2f[s], acc2, 0, 0, 0);
      #pragma unroll
      for (int r = 0; r < 4; r++)
        p[m][r] = fmaxf(acc2[r] + bb2, 0.f) * w3v;
    }
    // reduce over the 16 col-lanes of this wave
    #pragma unroll
    for (int msk = 1; msk < 16; msk <<= 1)
      #pragma unroll
      for (int m = 0; m < 4; m++)
        #pragma unroll
        for (int r = 0; r < 4; r++)
          p[m][r] += __shfl_xor(p[m][r], msk);
    if (c == 0){
      #pragma unroll
      for (int m = 0; m < 4; m++)
        #pragma unroll
        for (int r = 0; r < 4; r++)
          red[w][m*16 + 4*g + r] = p[m][r];
    }
    __syncthreads();
    if (t < 64){
      float s = b3s;
      #pragma unroll
      for (int j = 0; j < 16; j++) s += red[j][t];
      out[tile*64 + t] = s;
    }
    __syncthreads();
  }
}

extern "C" void kernel_launch(void* const* d_in, const int* in_sizes, int n_in,
                              void* d_out, int out_size, void* d_ws, size_t ws_size,
                              hipStream_t stream){
  if (ws_size < (size_t)WS_NEEDED) return;  // fail validation cleanly, don't fault
  const float* x      = (const float*)d_in[0];
  const int*   ei     = (const int*)  d_in[1];
  const int*   srcp   = ei;
  const int*   dstp   = ei + NE;
  const int*   fl     = (const int*)  d_in[2];
  const float* W_emd  = (const float*)d_in[3];
  const float* b_emd  = (const float*)d_in[4];
  const float* W_aggr = (const float*)d_in[5];
  const float* b_aggr = (const float*)d_in[6];
  const float* w_ih   = (const float*)d_in[7];
  const float* w_hh   = (const float*)d_in[8];
  const float* b_ih   = (const float*)d_in[9];
  const float* b_hh   = (const float*)d_in[10];
  const float* W1     = (const float*)d_in[11];
  const float* b1     = (const float*)d_in[12];
  const float* W2     = (const float*)d_in[13];
  const float* b2     = (const float*)d_in[14];
  const float* W3     = (const float*)d_in[15];
  const float* b3     = (const float*)d_in[16];

  char* ws = (char*)d_ws;
  _Float16* h16   = (_Float16*)(ws + OFF_H);
  int*   cso      = (int*)  (ws + OFF_CSO);
  int*   deg      = (int*)  (ws + OFF_DEG);
  int*   cur      = (int*)  (ws + OFF_CUR);
  int*   csr_pack = (int*)  (ws + OFF_CSRC);
  int*   bsum     = (int*)  (ws + OFF_BSUM);
  int*   node_list= (int*)  (ws + OFF_NLIST);
  _Float16* Wch   = (_Float16*)(ws + OFF_WCH);
  float* ghc      = (float*)(ws + OFF_GHC);
  float* mb       = (float*)(ws + OFF_MB);
  _Float16* W1h   = (_Float16*)(ws + OFF_W1H);
  _Float16* W2h   = (_Float16*)(ws + OFF_W2H);
  int*   cnt      = (int*)  (ws + OFF_CNT);
  float* outp     = (float*)d_out;

  const int nsb = (NN + SCB - 1)/SCB;   // 196 scan blocks

  (void)hipMemsetAsync(ws + OFF_CNT, 0, 512, stream);
  (void)hipMemsetAsync(ws + OFF_DEG, 0, 1600000, stream);   // deg + cur
  k_pre<<<2048, 256, 0, stream>>>(h16, fl, dstp, W_emd, b_emd, cnt, deg);
  k_scan<<<1, 64, 0, stream>>>(cnt);
  k_fill_n<<<196, 256, 0, stream>>>(fl, cnt, node_list);
  k_cscan1<<<nsb, SCB, 0, stream>>>(deg, cso, bsum);
  k_cscan2_prep<<<256, 256, 0, stream>>>(bsum, cso, nsb,
                                  w_ih, W_aggr, b_aggr, w_hh, W_emd, b_emd, b_hh,
                                  W1, W2, Wch, ghc, mb, W1h, W2h);
  k_cscan3<<<nsb, SCB, 0, stream>>>(cso, bsum);
  k_csr_fill<<<1024, 256, 0, stream>>>(srcp, dstp, fl, cso, cur, csr_pack);
  for (int l = 1; l < NLVL; l++)
    k_level_one<<<512, 512, 0, stream>>>(cnt, l, node_list, cso, csr_pack, x,
                                         Wch, ghc, mb, w_ih, b_ih, W_emd, b_emd, h16);
  k_mlp_pw<<<512, 1024, 0, stream>>>(h16, W1h, b1, W2h, b2, W3, b3, outp);
}

// Round 21
// 589.616 us; speedup vs baseline: 1.0551x; 1.0551x over previous
//
#include <hip/hip_runtime.h>

#define NN 200000
#define NE 600000
#define DD 128
#define DXX 3
#define DMM 256
#define NLVL 16

// ---- workspace byte offsets (total ~108.3 MB) ----
#define OFF_H      0LL                      // _Float16 h16[NN][128]     51,200,000
#define OFF_CSO    102400000LL              // int csr_off[NN+1]            800,016
#define OFF_DEG    103200016LL              // int deg[NN]                  800,000
#define OFF_CUR    104000016LL              // int cur[NN]                  800,000
#define OFF_CSRC   104800016LL              // int csr_pack[NE]           2,400,000
#define OFF_BSUM   107200016LL              // int bsum[256]                  1,024
#define OFF_NLIST  107201040LL              // int node_list[NN]            800,000
#define OFF_WCH    108001040LL              // _Float16 Wch[384][128]        98,304
#define OFF_GHC    108099344LL              // float ghc[384]                 1,536
#define OFF_MB     108100880LL              // float mb[384]                  1,536
#define OFF_W1H    108102416LL              // _Float16 W1h[256][128]        65,536
#define OFF_W2H    108167952LL              // _Float16 W2h[256][256]       131,072
#define OFF_CNT    108299024LL              // int counters[128]                512
#define WS_NEEDED  108299536LL

// cnt layout: [0..15] node_cnt  [32..48] node_start(17)  [66..81] node_cur

typedef float    f32x4 __attribute__((ext_vector_type(4)));
typedef _Float16 f16x8 __attribute__((ext_vector_type(8)));

__device__ __forceinline__ float sigm(float x){
  x = fminf(fmaxf(x, -30.f), 30.f);
  return 1.f/(1.f + __expf(-x));
}
__device__ __forceinline__ float tanh_(float x){
  x = fminf(fmaxf(x, -15.f), 15.f);
  float e = __expf(2.f*x);
  return (e - 1.f)/(e + 1.f);
}
__device__ __forceinline__ void acc8(float* acc, f16x8 v){
  for (int q = 0; q < 8; q++) acc[q] += (float)v[q];
}

// fused: init_h (fl==0 rows only) + node-level histogram + in-degree histogram
__global__ void k_pre(_Float16* h16, const int* fl, const int* dst,
                      const float* W_emd, const float* b_emd, int* cnt, int* deg){
  __shared__ int hn[NLVL];
  __shared__ _Float16 h0f[DD];
  if (threadIdx.x < NLVL) hn[threadIdx.x] = 0;
  if (threadIdx.x < DD) h0f[threadIdx.x] = (_Float16)(W_emd[threadIdx.x] + b_emd[threadIdx.x]);
  __syncthreads();
  const int tid = blockIdx.x*blockDim.x + threadIdx.x;
  const int stride = gridDim.x*blockDim.x;
  for (int i = tid; i < NN*16; i += stride){
    int row = i >> 4, ch = i & 15;
    if (fl[row] == 0)
      *(f16x8*)(h16 + (size_t)row*DD + ch*8) = *(const f16x8*)&h0f[ch*8];
  }
  for (int i = tid; i < NN; i += stride) atomicAdd(&hn[fl[i]], 1);
  for (int e = tid; e < NE; e += stride) atomicAdd(&deg[dst[e]], 1);
  __syncthreads();
  if (threadIdx.x < NLVL && hn[threadIdx.x])
    atomicAdd(&cnt[threadIdx.x], hn[threadIdx.x]);
}

__global__ void k_scan(int* cnt){
  if (threadIdx.x == 0){
    int s = 0;
    for (int l=0;l<NLVL;l++){ cnt[32+l] = s; s += cnt[l]; }
    cnt[48] = s;
    for (int l=0;l<NLVL;l++) cnt[66+l] = 0;
  }
}

// counting-sort fill of node_list (LDS hist + one global atomic per tile,level)
#define FB 1024
__global__ __launch_bounds__(256) void k_fill_n(const int* fl, int* cnt, int* node_list){
  __shared__ int hist[NLVL], base[NLVL];
  const int nt = (NN + FB - 1)/FB;
  for (int tile = blockIdx.x; tile < nt; tile += gridDim.x){
    const int i0 = tile*FB;
    if (threadIdx.x < NLVL) hist[threadIdx.x] = 0;
    __syncthreads();
    int lv[4], rk[4];
    #pragma unroll
    for (int j=0;j<4;j++){
      int i = i0 + threadIdx.x + j*256;
      if (i < NN){
        int l = fl[i];
        lv[j] = l;
        rk[j] = atomicAdd(&hist[l], 1);
      } else lv[j] = -1;
    }
    __syncthreads();
    if (threadIdx.x < NLVL)
      base[threadIdx.x] = atomicAdd(&cnt[66+threadIdx.x], hist[threadIdx.x]);
    __syncthreads();
    #pragma unroll
    for (int j=0;j<4;j++){
      if (lv[j] >= 0){
        int i = i0 + threadIdx.x + j*256;
        node_list[cnt[32+lv[j]] + base[lv[j]] + rk[j]] = i;
      }
    }
    __syncthreads();
  }
}

// 3-phase exclusive scan of deg -> csr_off
#define SCB 1024
__global__ __launch_bounds__(1024) void k_cscan1(const int* deg, int* cso, int* bsum){
  __shared__ int sh[SCB];
  const int b = blockIdx.x, t = threadIdx.x;
  const int i = b*SCB + t;
  int v = (i < NN) ? deg[i] : 0;
  sh[t] = v;
  __syncthreads();
  for (int ofs=1; ofs<SCB; ofs<<=1){
    int add = (t >= ofs) ? sh[t-ofs] : 0;
    __syncthreads();
    sh[t] += add;
    __syncthreads();
  }
  if (i < NN) cso[i] = sh[t] - v;   // exclusive
  if (t == SCB-1) bsum[b] = sh[t];
}

// fused: serial block-sum scan (1 thread) + weight precompute (all threads).
__global__ void k_cscan2_prep(int* bsum, int* cso, int nb,
                       const float* w_ih, const float* W_aggr, const float* b_aggr,
                       const float* w_hh, const float* W_emd, const float* b_emd,
                       const float* b_hh, const float* W1, const float* W2,
                       _Float16* Wch, float* ghc, float* mb,
                       _Float16* W1h, _Float16* W2h){
  if (blockIdx.x == 0 && threadIdx.x == 0){
    int run = 0;
    for (int b=0;b<nb;b++){ int tmp = bsum[b]; bsum[b] = run; run += tmp; }
    cso[NN] = run;
  }
  const int tid = blockIdx.x*blockDim.x + threadIdx.x;
  const int stride = gridDim.x*blockDim.x;
  for (int i = tid; i < 384*DD; i += stride){
    int r = i >> 7, k = i & (DD-1);
    float s = 0.f;
    for (int j=0;j<DD;j++) s += w_ih[r*(DD+DXX)+j]*W_aggr[j*DD+k];
    Wch[i] = (_Float16)s;          // [r][k] row-major
  }
  for (int i = tid; i < 384; i += stride){
    float s = 0.f, gg = 0.f;
    for (int j=0;j<DD;j++){
      s  += w_ih[i*(DD+DXX)+j]*b_aggr[j];
      gg += w_hh[i*DD+j]*(W_emd[j] + b_emd[j]);
    }
    mb[i]  = s;
    ghc[i] = gg + b_hh[i];
  }
  for (int i = tid; i < DMM*DD;  i += stride) W1h[i] = (_Float16)W1[i];
  for (int i = tid; i < DMM*DMM; i += stride) W2h[i] = (_Float16)W2[i];
}

__global__ __launch_bounds__(1024) void k_cscan3(int* cso, const int* bsum){
  const int i = blockIdx.x*SCB + threadIdx.x;
  if (i < NN) cso[i] += bsum[blockIdx.x];
}

// csr_pack[e] = src | (fl[src] << 24)
__global__ void k_csr_fill(const int* srcp, const int* dstp, const int* fl,
                           const int* cso, int* cur, int* csr_pack){
  for (int e = blockIdx.x*blockDim.x + threadIdx.x; e < NE; e += gridDim.x*blockDim.x){
    int d = dstp[e];
    int s = srcp[e];
    int p = atomicAdd(&cur[d], 1);
    csr_pack[cso[d] + p] = s | (fl[s] << 24);
  }
}

// ---- ONE level, fused gather + MFMA GRU; quad-batched pk loads.
// (512,6): ~85-VGPR cap (>= natural ~64, no spill) -> 3 blocks/CU = 24 waves.
#define GT 32
__global__ __launch_bounds__(512, 6) void k_level_one(const int* cnt, const int l,
    const int* node_list, const int* cso, const int* csr_pack,
    const float* x, const _Float16* Wch, const float* ghc, const float* mb,
    const float* w_ih, const float* b_ih, const float* W_emd, const float* b_emd,
    _Float16* h16){
  const int n0 = cnt[32+l];
  const int na = cnt[32+l+1] - n0;
  const int tb = blockIdx.x * GT;
  if (tb >= na) return;

  __shared__ float s_l[GT][DD+4];
  __shared__ float x_l[GT][4];
  __shared__ float deg_l[GT];
  __shared__ int   vidx[GT], eoff[GT], ecnt[GT];
  __shared__ float h0s[DD];
  const int t    = threadIdx.x;
  const int w    = t >> 6;
  const int lane = t & 63;
  const int c0   = lane & 15;
  const int g    = lane >> 4;
  const int jo   = w*16 + c0;

  if (t < DD) h0s[t] = W_emd[t] + b_emd[t];
  if (t < GT){
    int row = tb + t;
    int v = (row < na) ? node_list[n0 + row] : -1;
    vidx[t] = v;
    int e0 = 0, e1 = 0;
    if (v >= 0){ e0 = cso[v]; e1 = cso[v+1]; }
    eoff[t] = e0; ecnt[t] = e1 - e0;
    deg_l[t] = (float)(e1 - e0);
    for (int kx=0; kx<DXX; kx++) x_l[t][kx] = (v >= 0) ? x[v*DXX + kx] : 0.f;
  }

  // weight frags + scalars issued BEFORE the gather so both latencies overlap
  f16x8 wcf[3][4];
  #pragma unroll
  for (int gate = 0; gate < 3; gate++){
    const _Float16* wp = Wch + (size_t)(gate*128 + jo)*DD + 8*g;
    #pragma unroll
    for (int ks = 0; ks < 4; ks++) wcf[gate][ks] = *(const f16x8*)(wp + ks*32);
  }
  float biv[3], mbv[3], ghcv[3], wxv[3][3];
  #pragma unroll
  for (int gate = 0; gate < 3; gate++){
    biv[gate]  = b_ih[gate*128 + jo];
    mbv[gate]  = mb[gate*128 + jo];
    ghcv[gate] = ghc[gate*128 + jo];
    #pragma unroll
    for (int kx = 0; kx < 3; kx++)
      wxv[gate][kx] = w_ih[(size_t)(gate*128 + jo)*(DD+DXX) + DD + kx];
  }
  const float h0v = W_emd[jo] + b_emd[jo];
  __syncthreads();

  // gather: 16 threads/row, dims [8*sub, 8*sub+8); quad-batched independent
  // pk loads then all eligible h loads in flight; f32 accumulate.
  {
    const int j = t >> 4, sub = t & 15;
    const int v = vidx[j];
    float acc[8] = {0,0,0,0,0,0,0,0};
    int nh0 = 0;
    if (v >= 0){
      const int e0 = eoff[j], n = ecnt[j];
      int i = 0;
      for (; i + 4 <= n; i += 4){
        int p0 = csr_pack[e0+i+0];
        int p1 = csr_pack[e0+i+1];
        int p2 = csr_pack[e0+i+2];
        int p3 = csr_pack[e0+i+3];
        int f0=p0>>24, f1=p1>>24, f2=p2>>24, f3=p3>>24;
        bool d0=(f0!=0)&(f0<l), d1=(f1!=0)&(f1<l), d2=(f2!=0)&(f2<l), d3=(f3!=0)&(f3<l);
        f16x8 v0, v1, v2, v3;
        if (d0) v0 = *(const f16x8*)(h16 + (size_t)(p0 & 0xFFFFFF)*DD + sub*8); else nh0++;
        if (d1) v1 = *(const f16x8*)(h16 + (size_t)(p1 & 0xFFFFFF)*DD + sub*8); else nh0++;
        if (d2) v2 = *(const f16x8*)(h16 + (size_t)(p2 & 0xFFFFFF)*DD + sub*8); else nh0++;
        if (d3) v3 = *(const f16x8*)(h16 + (size_t)(p3 & 0xFFFFFF)*DD + sub*8); else nh0++;
        if (d0) acc8(acc, v0);
        if (d1) acc8(acc, v1);
        if (d2) acc8(acc, v2);
        if (d3) acc8(acc, v3);
      }
      const int r = n - i;   // 0..3 tail: all pk loads first, then h loads
      if (r > 0){
        int p0 = csr_pack[e0+i];
        int p1 = (r > 1) ? csr_pack[e0+i+1] : 0;
        int p2 = (r > 2) ? csr_pack[e0+i+2] : 0;
        int f0=p0>>24, f1=p1>>24, f2=p2>>24;
        bool d0=(f0!=0)&(f0<l);
        bool d1=(r>1)&(f1!=0)&(f1<l);
        bool d2=(r>2)&(f2!=0)&(f2<l);
        f16x8 v0, v1, v2;
        if (d0) v0 = *(const f16x8*)(h16 + (size_t)(p0 & 0xFFFFFF)*DD + sub*8);
        if (d1) v1 = *(const f16x8*)(h16 + (size_t)(p1 & 0xFFFFFF)*DD + sub*8);
        if (d2) v2 = *(const f16x8*)(h16 + (size_t)(p2 & 0xFFFFFF)*DD + sub*8);
        nh0 += (d0?0:1) + ((r>1)?(d1?0:1):0) + ((r>2)?(d2?0:1):0);
        if (d0) acc8(acc, v0);
        if (d1) acc8(acc, v1);
        if (d2) acc8(acc, v2);
      }
      if (nh0){
        float nh = (float)nh0;
        for (int q=0;q<8;q++) acc[q] += nh*h0s[sub*8+q];
      }
    }
    *(float4*)&s_l[j][sub*8]     = make_float4(acc[0],acc[1],acc[2],acc[3]);
    *(float4*)&s_l[j][sub*8 + 4] = make_float4(acc[4],acc[5],acc[6],acc[7]);
  }
  __syncthreads();

  // MFMA GRU (gi only; gh == ghc const); 32 rows = 2 m-tiles
  #pragma unroll
  for (int m = 0; m < 2; m++){
    const int a_row = m*16 + c0;
    f16x8 as[4];
    #pragma unroll
    for (int ks = 0; ks < 4; ks++){
      const float* sp = &s_l[a_row][ks*32 + 8*g];
      f16x8 av;
      #pragma unroll
      for (int i2 = 0; i2 < 8; i2++) av[i2] = (_Float16)sp[i2];
      as[ks] = av;
    }
    f32x4 gi[3];
    #pragma unroll
    for (int gate = 0; gate < 3; gate++) gi[gate] = (f32x4){0.f,0.f,0.f,0.f};
    #pragma unroll
    for (int gate = 0; gate < 3; gate++)
      #pragma unroll
      for (int ks = 0; ks < 4; ks++)
        gi[gate] = __builtin_amdgcn_mfma_f32_16x16x32_f16(as[ks], wcf[gate][ks], gi[gate], 0, 0, 0);
    #pragma unroll
    for (int r = 0; r < 4; r++){
      const int node = m*16 + 4*g + r;
      const int v = vidx[node];
      if (v < 0) continue;
      const float dg = deg_l[node];
      float xr = 0.f, xz = 0.f, xn = 0.f;
      #pragma unroll
      for (int kx = 0; kx < 3; kx++){
        float xv = x_l[node][kx];
        xr = fmaf(wxv[0][kx], xv, xr);
        xz = fmaf(wxv[1][kx], xv, xz);
        xn = fmaf(wxv[2][kx], xv, xn);
      }
      float grv = gi[0][r] + biv[0] + dg*mbv[0] + xr + ghcv[0];
      float gzv = gi[1][r] + biv[1] + dg*mbv[1] + xz + ghcv[1];
      float rr = sigm(grv);
      float zz = sigm(gzv);
      float gnv = gi[2][r] + biv[2] + dg*mbv[2] + xn + rr*ghcv[2];
      float nv = tanh_(gnv);
      h16[(size_t)v*DD + jo] = (_Float16)((1.f - zz)*nv + zz*h0v);
    }
  }
}

// MFMA MLP, 16 waves/block; wave w owns cols [16w,16w+16) of both layers.
// r13 config restored: grid 256, (1024,1) -> 128-VGPR cap (weights fit, no
// spill; the r17 (1024,8) forced 32 VGPR and re-streamed 600MB of weights).
// Plus register prefetch: next tile's 16B/thread loads during compute.
__global__ __launch_bounds__(1024, 1) void k_mlp_pw(const _Float16* __restrict__ h16,
    const _Float16* __restrict__ W1h, const float* __restrict__ b1,
    const _Float16* __restrict__ W2h, const float* __restrict__ b2,
    const float* __restrict__ W3, const float* __restrict__ b3,
    float* __restrict__ out){
  __shared__ _Float16 hA[64*128];    // 16 KB swizzled (byte ^= (row&7)<<4, 256B rows)
  __shared__ _Float16 h1s[64*256];   // 32 KB swizzled (512B rows)
  __shared__ float red[16][64];      // 4 KB
  const int t    = threadIdx.x;
  const int w    = t >> 6;           // 0..15
  const int lane = t & 63;
  const int c    = lane & 15;
  const int g    = lane >> 4;
  const int col  = w*16 + c;         // this wave-lane's output column (both layers)

  f16x8 w1f[4], w2f[8];
  #pragma unroll
  for (int s = 0; s < 4; s++) w1f[s] = *(const f16x8*)(W1h + (size_t)col*DD  + s*32 + 8*g);
  #pragma unroll
  for (int s = 0; s < 8; s++) w2f[s] = *(const f16x8*)(W2h + (size_t)col*DMM + s*32 + 8*g);
  const float bb1 = b1[col], bb2 = b2[col], w3v = W3[col], b3s = b3[0];

  // swizzled LDS slot for this thread's stage chunk
  const int sbyte = t*16;
  const int srow  = sbyte >> 8;
  const int sswz  = sbyte ^ ((srow & 7) << 4);

  const int NT = NN/64;
  f16x8 stg = ((const f16x8*)(h16 + (size_t)blockIdx.x*64*DD))[t];  // first tile

  for (int tile = blockIdx.x; tile < NT; tile += gridDim.x){
    *(f16x8*)((char*)hA + sswz) = stg;
    __syncthreads();
    // issue next tile's stage load NOW; it completes during compute below
    {
      int nxt = tile + gridDim.x;
      if (nxt < NT) stg = ((const f16x8*)(h16 + (size_t)nxt*64*DD))[t];
    }

    // layer 1: acc[m] (16 rows x this lane's col), K=128
    f32x4 acc[4];
    #pragma unroll
    for (int m = 0; m < 4; m++){
      acc[m] = (f32x4){0.f,0.f,0.f,0.f};
      int row = m*16 + c;
      #pragma unroll
      for (int s = 0; s < 4; s++){
        int byte = row*256 + ((g*16 + s*64) ^ ((row & 7) << 4));
        f16x8 a1 = *(const f16x8*)((const char*)hA + byte);
        acc[m] = __builtin_amdgcn_mfma_f32_16x16x32_f16(a1, w1f[s], acc[m], 0, 0, 0);
      }
    }
    // h1 = relu(acc+b1) -> swizzled LDS (row 512B)
    #pragma unroll
    for (int m = 0; m < 4; m++)
      #pragma unroll
      for (int r = 0; r < 4; r++){
        int row = m*16 + 4*g + r;
        int off = (row*512 + col*2) ^ ((row & 7) << 4);
        *(_Float16*)((char*)h1s + off) = (_Float16)fmaxf(acc[m][r] + bb1, 0.f);
      }
    __syncthreads();

    // layer 2 + 3
    float p[4][4];
    #pragma unroll
    for (int m = 0; m < 4; m++){
      int row = m*16 + c;
      f16x8 a2[8];
      #pragma unroll
      for (int s = 0; s < 8; s++){
        int off = (row*512 + s*64 + g*16) ^ ((row & 7) << 4);
        a2[s] = *(const f16x8*)((const char*)h1s + off);
      }
      f32x4 acc2 = (f32x4){0.f,0.f,0.f,0.f};
      #pragma unroll
      for (int s = 0; s < 8; s++)
        acc2 = __builtin_amdgcn_mfma_f32_16x16x32_f16(a2[s], w2f[s], acc2, 0, 0, 0);
      #pragma unroll
      for (int r = 0; r < 4; r++)
        p[m][r] = fmaxf(acc2[r] + bb2, 0.f) * w3v;
    }
    // reduce over the 16 col-lanes of this wave
    #pragma unroll
    for (int msk = 1; msk < 16; msk <<= 1)
      #pragma unroll
      for (int m = 0; m < 4; m++)
        #pragma unroll
        for (int r = 0; r < 4; r++)
          p[m][r] += __shfl_xor(p[m][r], msk);
    if (c == 0){
      #pragma unroll
      for (int m = 0; m < 4; m++)
        #pragma unroll
        for (int r = 0; r < 4; r++)
          red[w][m*16 + 4*g + r] = p[m][r];
    }
    __syncthreads();
    if (t < 64){
      float s = b3s;
      #pragma unroll
      for (int j = 0; j < 16; j++) s += red[j][t];
      out[tile*64 + t] = s;
    }
    __syncthreads();
  }
}

extern "C" void kernel_launch(void* const* d_in, const int* in_sizes, int n_in,
                              void* d_out, int out_size, void* d_ws, size_t ws_size,
                              hipStream_t stream){
  if (ws_size < (size_t)WS_NEEDED) return;  // fail validation cleanly, don't fault
  const float* x      = (const float*)d_in[0];
  const int*   ei     = (const int*)  d_in[1];
  const int*   srcp   = ei;
  const int*   dstp   = ei + NE;
  const int*   fl     = (const int*)  d_in[2];
  const float* W_emd  = (const float*)d_in[3];
  const float* b_emd  = (const float*)d_in[4];
  const float* W_aggr = (const float*)d_in[5];
  const float* b_aggr = (const float*)d_in[6];
  const float* w_ih   = (const float*)d_in[7];
  const float* w_hh   = (const float*)d_in[8];
  const float* b_ih   = (const float*)d_in[9];
  const float* b_hh   = (const float*)d_in[10];
  const float* W1     = (const float*)d_in[11];
  const float* b1     = (const float*)d_in[12];
  const float* W2     = (const float*)d_in[13];
  const float* b2     = (const float*)d_in[14];
  const float* W3     = (const float*)d_in[15];
  const float* b3     = (const float*)d_in[16];

  char* ws = (char*)d_ws;
  _Float16* h16   = (_Float16*)(ws + OFF_H);
  int*   cso      = (int*)  (ws + OFF_CSO);
  int*   deg      = (int*)  (ws + OFF_DEG);
  int*   cur      = (int*)  (ws + OFF_CUR);
  int*   csr_pack = (int*)  (ws + OFF_CSRC);
  int*   bsum     = (int*)  (ws + OFF_BSUM);
  int*   node_list= (int*)  (ws + OFF_NLIST);
  _Float16* Wch   = (_Float16*)(ws + OFF_WCH);
  float* ghc      = (float*)(ws + OFF_GHC);
  float* mb       = (float*)(ws + OFF_MB);
  _Float16* W1h   = (_Float16*)(ws + OFF_W1H);
  _Float16* W2h   = (_Float16*)(ws + OFF_W2H);
  int*   cnt      = (int*)  (ws + OFF_CNT);
  float* outp     = (float*)d_out;

  const int nsb = (NN + SCB - 1)/SCB;   // 196 scan blocks

  (void)hipMemsetAsync(ws + OFF_CNT, 0, 512, stream);
  (void)hipMemsetAsync(ws + OFF_DEG, 0, 1600000, stream);   // deg + cur
  k_pre<<<2048, 256, 0, stream>>>(h16, fl, dstp, W_emd, b_emd, cnt, deg);
  k_scan<<<1, 64, 0, stream>>>(cnt);
  k_fill_n<<<196, 256, 0, stream>>>(fl, cnt, node_list);
  k_cscan1<<<nsb, SCB, 0, stream>>>(deg, cso, bsum);
  k_cscan2_prep<<<256, 256, 0, stream>>>(bsum, cso, nsb,
                                  w_ih, W_aggr, b_aggr, w_hh, W_emd, b_emd, b_hh,
                                  W1, W2, Wch, ghc, mb, W1h, W2h);
  k_cscan3<<<nsb, SCB, 0, stream>>>(cso, bsum);
  k_csr_fill<<<1024, 256, 0, stream>>>(srcp, dstp, fl, cso, cur, csr_pack);
  for (int l = 1; l < NLVL; l++)
    k_level_one<<<512, 512, 0, stream>>>(cnt, l, node_list, cso, csr_pack, x,
                                         Wch, ghc, mb, w_ih, b_ih, W_emd, b_emd, h16);
  k_mlp_pw<<<256, 1024, 0, stream>>>(h16, W1h, b1, W2h, b2, W3, b3, outp);
}

// Round 22
// 493.057 us; speedup vs baseline: 1.2618x; 1.1958x over previous
//
#include <hip/hip_runtime.h>

#define NN 200000
#define NE 600000
#define DD 128
#define DXX 3
#define DMM 256
#define NLVL 16

// ---- workspace byte offsets (total ~108.3 MB) ----
#define OFF_H      0LL                      // _Float16 h16[NN][128]     51,200,000
#define OFF_CSO    102400000LL              // int csr_off[NN+1]            800,016
#define OFF_DEG    103200016LL              // int deg[NN]                  800,000
#define OFF_CUR    104000016LL              // int cur[NN]                  800,000
#define OFF_CSRC   104800016LL              // int csr_pack[NE]           2,400,000
#define OFF_BSUM   107200016LL              // int bsum[256]                  1,024
#define OFF_NLIST  107201040LL              // int node_list[NN]            800,000
#define OFF_WCH    108001040LL              // _Float16 Wch[384][128]        98,304
#define OFF_GHC    108099344LL              // float ghc[384]                 1,536
#define OFF_MB     108100880LL              // float mb[384]                  1,536
#define OFF_W1H    108102416LL              // _Float16 W1h[256][128]        65,536
#define OFF_W2H    108167952LL              // _Float16 W2h[256][256]       131,072
#define OFF_CNT    108299024LL              // int counters[128]                512
#define WS_NEEDED  108299536LL

// cnt layout: [0..15] node_cnt  [32..48] node_start(17)  [66..81] node_cur

typedef float    f32x4 __attribute__((ext_vector_type(4)));
typedef _Float16 f16x8 __attribute__((ext_vector_type(8)));

__device__ __forceinline__ float sigm(float x){
  x = fminf(fmaxf(x, -30.f), 30.f);
  return 1.f/(1.f + __expf(-x));
}
__device__ __forceinline__ float tanh_(float x){
  x = fminf(fmaxf(x, -15.f), 15.f);
  float e = __expf(2.f*x);
  return (e - 1.f)/(e + 1.f);
}
__device__ __forceinline__ void acc8(float* acc, f16x8 v){
  for (int q = 0; q < 8; q++) acc[q] += (float)v[q];
}

// fused: init_h (fl==0 rows only) + node-level histogram + in-degree histogram
__global__ void k_pre(_Float16* h16, const int* fl, const int* dst,
                      const float* W_emd, const float* b_emd, int* cnt, int* deg){
  __shared__ int hn[NLVL];
  __shared__ _Float16 h0f[DD];
  if (threadIdx.x < NLVL) hn[threadIdx.x] = 0;
  if (threadIdx.x < DD) h0f[threadIdx.x] = (_Float16)(W_emd[threadIdx.x] + b_emd[threadIdx.x]);
  __syncthreads();
  const int tid = blockIdx.x*blockDim.x + threadIdx.x;
  const int stride = gridDim.x*blockDim.x;
  for (int i = tid; i < NN*16; i += stride){
    int row = i >> 4, ch = i & 15;
    if (fl[row] == 0)
      *(f16x8*)(h16 + (size_t)row*DD + ch*8) = *(const f16x8*)&h0f[ch*8];
  }
  for (int i = tid; i < NN; i += stride) atomicAdd(&hn[fl[i]], 1);
  for (int e = tid; e < NE; e += stride) atomicAdd(&deg[dst[e]], 1);
  __syncthreads();
  if (threadIdx.x < NLVL && hn[threadIdx.x])
    atomicAdd(&cnt[threadIdx.x], hn[threadIdx.x]);
}

__global__ void k_scan(int* cnt){
  if (threadIdx.x == 0){
    int s = 0;
    for (int l=0;l<NLVL;l++){ cnt[32+l] = s; s += cnt[l]; }
    cnt[48] = s;
    for (int l=0;l<NLVL;l++) cnt[66+l] = 0;
  }
}

// counting-sort fill of node_list (LDS hist + one global atomic per tile,level)
#define FB 1024
__global__ __launch_bounds__(256) void k_fill_n(const int* fl, int* cnt, int* node_list){
  __shared__ int hist[NLVL], base[NLVL];
  const int nt = (NN + FB - 1)/FB;
  for (int tile = blockIdx.x; tile < nt; tile += gridDim.x){
    const int i0 = tile*FB;
    if (threadIdx.x < NLVL) hist[threadIdx.x] = 0;
    __syncthreads();
    int lv[4], rk[4];
    #pragma unroll
    for (int j=0;j<4;j++){
      int i = i0 + threadIdx.x + j*256;
      if (i < NN){
        int l = fl[i];
        lv[j] = l;
        rk[j] = atomicAdd(&hist[l], 1);
      } else lv[j] = -1;
    }
    __syncthreads();
    if (threadIdx.x < NLVL)
      base[threadIdx.x] = atomicAdd(&cnt[66+threadIdx.x], hist[threadIdx.x]);
    __syncthreads();
    #pragma unroll
    for (int j=0;j<4;j++){
      if (lv[j] >= 0){
        int i = i0 + threadIdx.x + j*256;
        node_list[cnt[32+lv[j]] + base[lv[j]] + rk[j]] = i;
      }
    }
    __syncthreads();
  }
}

// 3-phase exclusive scan of deg -> csr_off
#define SCB 1024
__global__ __launch_bounds__(1024) void k_cscan1(const int* deg, int* cso, int* bsum){
  __shared__ int sh[SCB];
  const int b = blockIdx.x, t = threadIdx.x;
  const int i = b*SCB + t;
  int v = (i < NN) ? deg[i] : 0;
  sh[t] = v;
  __syncthreads();
  for (int ofs=1; ofs<SCB; ofs<<=1){
    int add = (t >= ofs) ? sh[t-ofs] : 0;
    __syncthreads();
    sh[t] += add;
    __syncthreads();
  }
  if (i < NN) cso[i] = sh[t] - v;   // exclusive
  if (t == SCB-1) bsum[b] = sh[t];
}

// fused: serial block-sum scan (1 thread) + weight precompute (all threads).
__global__ void k_cscan2_prep(int* bsum, int* cso, int nb,
                       const float* w_ih, const float* W_aggr, const float* b_aggr,
                       const float* w_hh, const float* W_emd, const float* b_emd,
                       const float* b_hh, const float* W1, const float* W2,
                       _Float16* Wch, float* ghc, float* mb,
                       _Float16* W1h, _Float16* W2h){
  if (blockIdx.x == 0 && threadIdx.x == 0){
    int run = 0;
    for (int b=0;b<nb;b++){ int tmp = bsum[b]; bsum[b] = run; run += tmp; }
    cso[NN] = run;
  }
  const int tid = blockIdx.x*blockDim.x + threadIdx.x;
  const int stride = gridDim.x*blockDim.x;
  for (int i = tid; i < 384*DD; i += stride){
    int r = i >> 7, k = i & (DD-1);
    float s = 0.f;
    for (int j=0;j<DD;j++) s += w_ih[r*(DD+DXX)+j]*W_aggr[j*DD+k];
    Wch[i] = (_Float16)s;          // [r][k] row-major
  }
  for (int i = tid; i < 384; i += stride){
    float s = 0.f, gg = 0.f;
    for (int j=0;j<DD;j++){
      s  += w_ih[i*(DD+DXX)+j]*b_aggr[j];
      gg += w_hh[i*DD+j]*(W_emd[j] + b_emd[j]);
    }
    mb[i]  = s;
    ghc[i] = gg + b_hh[i];
  }
  for (int i = tid; i < DMM*DD;  i += stride) W1h[i] = (_Float16)W1[i];
  for (int i = tid; i < DMM*DMM; i += stride) W2h[i] = (_Float16)W2[i];
}

__global__ __launch_bounds__(1024) void k_cscan3(int* cso, const int* bsum){
  const int i = blockIdx.x*SCB + threadIdx.x;
  if (i < NN) cso[i] += bsum[blockIdx.x];
}

// csr_pack[e] = src | (fl[src] << 24)
__global__ void k_csr_fill(const int* srcp, const int* dstp, const int* fl,
                           const int* cso, int* cur, int* csr_pack){
  for (int e = blockIdx.x*blockDim.x + threadIdx.x; e < NE; e += gridDim.x*blockDim.x){
    int d = dstp[e];
    int s = srcp[e];
    int p = atomicAdd(&cur[d], 1);
    csr_pack[cso[d] + p] = s | (fl[s] << 24);
  }
}

// ---- ONE level, fused gather + MFMA GRU; quad-batched pk loads
#define GT 32
__global__ __launch_bounds__(512, 4) void k_level_one(const int* cnt, const int l,
    const int* node_list, const int* cso, const int* csr_pack,
    const float* x, const _Float16* Wch, const float* ghc, const float* mb,
    const float* w_ih, const float* b_ih, const float* W_emd, const float* b_emd,
    _Float16* h16){
  const int n0 = cnt[32+l];
  const int na = cnt[32+l+1] - n0;
  const int tb = blockIdx.x * GT;
  if (tb >= na) return;

  __shared__ float s_l[GT][DD+4];
  __shared__ float x_l[GT][4];
  __shared__ float deg_l[GT];
  __shared__ int   vidx[GT], eoff[GT], ecnt[GT];
  __shared__ float h0s[DD];
  const int t    = threadIdx.x;
  const int w    = t >> 6;
  const int lane = t & 63;
  const int c0   = lane & 15;
  const int g    = lane >> 4;
  const int jo   = w*16 + c0;

  if (t < DD) h0s[t] = W_emd[t] + b_emd[t];
  if (t < GT){
    int row = tb + t;
    int v = (row < na) ? node_list[n0 + row] : -1;
    vidx[t] = v;
    int e0 = 0, e1 = 0;
    if (v >= 0){ e0 = cso[v]; e1 = cso[v+1]; }
    eoff[t] = e0; ecnt[t] = e1 - e0;
    deg_l[t] = (float)(e1 - e0);
    for (int kx=0; kx<DXX; kx++) x_l[t][kx] = (v >= 0) ? x[v*DXX + kx] : 0.f;
  }

  // weight frags + scalars issued BEFORE the gather so both latencies overlap
  f16x8 wcf[3][4];
  #pragma unroll
  for (int gate = 0; gate < 3; gate++){
    const _Float16* wp = Wch + (size_t)(gate*128 + jo)*DD + 8*g;
    #pragma unroll
    for (int ks = 0; ks < 4; ks++) wcf[gate][ks] = *(const f16x8*)(wp + ks*32);
  }
  float biv[3], mbv[3], ghcv[3], wxv[3][3];
  #pragma unroll
  for (int gate = 0; gate < 3; gate++){
    biv[gate]  = b_ih[gate*128 + jo];
    mbv[gate]  = mb[gate*128 + jo];
    ghcv[gate] = ghc[gate*128 + jo];
    #pragma unroll
    for (int kx = 0; kx < 3; kx++)
      wxv[gate][kx] = w_ih[(size_t)(gate*128 + jo)*(DD+DXX) + DD + kx];
  }
  const float h0v = W_emd[jo] + b_emd[jo];
  __syncthreads();

  // gather: 16 threads/row, dims [8*sub, 8*sub+8); quad-batched independent
  // pk loads then all eligible h loads in flight; f32 accumulate.
  {
    const int j = t >> 4, sub = t & 15;
    const int v = vidx[j];
    float acc[8] = {0,0,0,0,0,0,0,0};
    int nh0 = 0;
    if (v >= 0){
      const int e0 = eoff[j], n = ecnt[j];
      int i = 0;
      for (; i + 4 <= n; i += 4){
        int p0 = csr_pack[e0+i+0];
        int p1 = csr_pack[e0+i+1];
        int p2 = csr_pack[e0+i+2];
        int p3 = csr_pack[e0+i+3];
        int f0=p0>>24, f1=p1>>24, f2=p2>>24, f3=p3>>24;
        bool d0=(f0!=0)&(f0<l), d1=(f1!=0)&(f1<l), d2=(f2!=0)&(f2<l), d3=(f3!=0)&(f3<l);
        f16x8 v0, v1, v2, v3;
        if (d0) v0 = *(const f16x8*)(h16 + (size_t)(p0 & 0xFFFFFF)*DD + sub*8); else nh0++;
        if (d1) v1 = *(const f16x8*)(h16 + (size_t)(p1 & 0xFFFFFF)*DD + sub*8); else nh0++;
        if (d2) v2 = *(const f16x8*)(h16 + (size_t)(p2 & 0xFFFFFF)*DD + sub*8); else nh0++;
        if (d3) v3 = *(const f16x8*)(h16 + (size_t)(p3 & 0xFFFFFF)*DD + sub*8); else nh0++;
        if (d0) acc8(acc, v0);
        if (d1) acc8(acc, v1);
        if (d2) acc8(acc, v2);
        if (d3) acc8(acc, v3);
      }
      const int r = n - i;   // 0..3 tail: all pk loads first, then h loads
      if (r > 0){
        int p0 = csr_pack[e0+i];
        int p1 = (r > 1) ? csr_pack[e0+i+1] : 0;
        int p2 = (r > 2) ? csr_pack[e0+i+2] : 0;
        int f0=p0>>24, f1=p1>>24, f2=p2>>24;
        bool d0=(f0!=0)&(f0<l);
        bool d1=(r>1)&(f1!=0)&(f1<l);
        bool d2=(r>2)&(f2!=0)&(f2<l);
        f16x8 v0, v1, v2;
        if (d0) v0 = *(const f16x8*)(h16 + (size_t)(p0 & 0xFFFFFF)*DD + sub*8);
        if (d1) v1 = *(const f16x8*)(h16 + (size_t)(p1 & 0xFFFFFF)*DD + sub*8);
        if (d2) v2 = *(const f16x8*)(h16 + (size_t)(p2 & 0xFFFFFF)*DD + sub*8);
        nh0 += (d0?0:1) + ((r>1)?(d1?0:1):0) + ((r>2)?(d2?0:1):0);
        if (d0) acc8(acc, v0);
        if (d1) acc8(acc, v1);
        if (d2) acc8(acc, v2);
      }
      if (nh0){
        float nh = (float)nh0;
        for (int q=0;q<8;q++) acc[q] += nh*h0s[sub*8+q];
      }
    }
    *(float4*)&s_l[j][sub*8]     = make_float4(acc[0],acc[1],acc[2],acc[3]);
    *(float4*)&s_l[j][sub*8 + 4] = make_float4(acc[4],acc[5],acc[6],acc[7]);
  }
  __syncthreads();

  // MFMA GRU (gi only; gh == ghc const); 32 rows = 2 m-tiles
  #pragma unroll
  for (int m = 0; m < 2; m++){
    const int a_row = m*16 + c0;
    f16x8 as[4];
    #pragma unroll
    for (int ks = 0; ks < 4; ks++){
      const float* sp = &s_l[a_row][ks*32 + 8*g];
      f16x8 av;
      #pragma unroll
      for (int i2 = 0; i2 < 8; i2++) av[i2] = (_Float16)sp[i2];
      as[ks] = av;
    }
    f32x4 gi[3];
    #pragma unroll
    for (int gate = 0; gate < 3; gate++) gi[gate] = (f32x4){0.f,0.f,0.f,0.f};
    #pragma unroll
    for (int gate = 0; gate < 3; gate++)
      #pragma unroll
      for (int ks = 0; ks < 4; ks++)
        gi[gate] = __builtin_amdgcn_mfma_f32_16x16x32_f16(as[ks], wcf[gate][ks], gi[gate], 0, 0, 0);
    #pragma unroll
    for (int r = 0; r < 4; r++){
      const int node = m*16 + 4*g + r;
      const int v = vidx[node];
      if (v < 0) continue;
      const float dg = deg_l[node];
      float xr = 0.f, xz = 0.f, xn = 0.f;
      #pragma unroll
      for (int kx = 0; kx < 3; kx++){
        float xv = x_l[node][kx];
        xr = fmaf(wxv[0][kx], xv, xr);
        xz = fmaf(wxv[1][kx], xv, xz);
        xn = fmaf(wxv[2][kx], xv, xn);
      }
      float grv = gi[0][r] + biv[0] + dg*mbv[0] + xr + ghcv[0];
      float gzv = gi[1][r] + biv[1] + dg*mbv[1] + xz + ghcv[1];
      float rr = sigm(grv);
      float zz = sigm(gzv);
      float gnv = gi[2][r] + biv[2] + dg*mbv[2] + xn + rr*ghcv[2];
      float nv = tanh_(gnv);
      h16[(size_t)v*DD + jo] = (_Float16)((1.f - zz)*nv + zz*h0v);
    }
  }
}

// MFMA MLP, 16 waves/block; wave w owns cols [16w,16w+16) of both layers
// (48 VGPR of truly loop-invariant weights). (1024,1): 128-VGPR cap, no spill.
__global__ __launch_bounds__(1024, 1) void k_mlp_pw(const _Float16* __restrict__ h16,
    const _Float16* __restrict__ W1h, const float* __restrict__ b1,
    const _Float16* __restrict__ W2h, const float* __restrict__ b2,
    const float* __restrict__ W3, const float* __restrict__ b3,
    float* __restrict__ out){
  __shared__ _Float16 hA[64*128];    // 16 KB swizzled (byte ^= (row&7)<<4, 256B rows)
  __shared__ _Float16 h1s[64*256];   // 32 KB swizzled (512B rows)
  __shared__ float red[16][64];      // 4 KB
  const int t    = threadIdx.x;
  const int w    = t >> 6;           // 0..15
  const int lane = t & 63;
  const int c    = lane & 15;
  const int g    = lane >> 4;
  const int col  = w*16 + c;         // this wave-lane's output column (both layers)

  f16x8 w1f[4], w2f[8];
  #pragma unroll
  for (int s = 0; s < 4; s++) w1f[s] = *(const f16x8*)(W1h + (size_t)col*DD  + s*32 + 8*g);
  #pragma unroll
  for (int s = 0; s < 8; s++) w2f[s] = *(const f16x8*)(W2h + (size_t)col*DMM + s*32 + 8*g);
  const float bb1 = b1[col], bb2 = b2[col], w3v = W3[col], b3s = b3[0];

  for (int tile = blockIdx.x; tile < NN/64; tile += gridDim.x){
    const int base = tile*64;
    // stage 16KB: 1024 threads x 16B contiguous
    {
      int byte = t*16;
      int row  = byte >> 8;
      int swz  = byte ^ ((row & 7) << 4);
      *(f16x8*)((char*)hA + swz) = ((const f16x8*)(h16 + (size_t)base*DD))[t];
    }
    __syncthreads();

    // layer 1: acc[m] (16 rows x this lane's col), K=128
    f32x4 acc[4];
    #pragma unroll
    for (int m = 0; m < 4; m++){
      acc[m] = (f32x4){0.f,0.f,0.f,0.f};
      int row = m*16 + c;
      #pragma unroll
      for (int s = 0; s < 4; s++){
        int byte = row*256 + ((g*16 + s*64) ^ ((row & 7) << 4));
        f16x8 a1 = *(const f16x8*)((const char*)hA + byte);
        acc[m] = __builtin_amdgcn_mfma_f32_16x16x32_f16(a1, w1f[s], acc[m], 0, 0, 0);
      }
    }
    // h1 = relu(acc+b1) -> swizzled LDS (row 512B)
    #pragma unroll
    for (int m = 0; m < 4; m++)
      #pragma unroll
      for (int r = 0; r < 4; r++){
        int row = m*16 + 4*g + r;
        int off = (row*512 + col*2) ^ ((row & 7) << 4);
        *(_Float16*)((char*)h1s + off) = (_Float16)fmaxf(acc[m][r] + bb1, 0.f);
      }
    __syncthreads();

    // layer 2 + 3
    float p[4][4];
    #pragma unroll
    for (int m = 0; m < 4; m++){
      int row = m*16 + c;
      f16x8 a2[8];
      #pragma unroll
      for (int s = 0; s < 8; s++){
        int off = (row*512 + s*64 + g*16) ^ ((row & 7) << 4);
        a2[s] = *(const f16x8*)((const char*)h1s + off);
      }
      f32x4 acc2 = (f32x4){0.f,0.f,0.f,0.f};
      #pragma unroll
      for (int s = 0; s < 8; s++)
        acc2 = __builtin_amdgcn_mfma_f32_16x16x32_f16(a2[s], w2f[s], acc2, 0, 0, 0);
      #pragma unroll
      for (int r = 0; r < 4; r++)
        p[m][r] = fmaxf(acc2[r] + bb2, 0.f) * w3v;
    }
    // reduce over the 16 col-lanes of this wave
    #pragma unroll
    for (int msk = 1; msk < 16; msk <<= 1)
      #pragma unroll
      for (int m = 0; m < 4; m++)
        #pragma unroll
        for (int r = 0; r < 4; r++)
          p[m][r] += __shfl_xor(p[m][r], msk);
    if (c == 0){
      #pragma unroll
      for (int m = 0; m < 4; m++)
        #pragma unroll
        for (int r = 0; r < 4; r++)
          red[w][m*16 + 4*g + r] = p[m][r];
    }
    __syncthreads();
    if (t < 64){
      float s = b3s;
      #pragma unroll
      for (int j = 0; j < 16; j++) s += red[j][t];
      out[base + t] = s;
    }
    __syncthreads();
  }
}

extern "C" void kernel_launch(void* const* d_in, const int* in_sizes, int n_in,
                              void* d_out, int out_size, void* d_ws, size_t ws_size,
                              hipStream_t stream){
  if (ws_size < (size_t)WS_NEEDED) return;  // fail validation cleanly, don't fault
  const float* x      = (const float*)d_in[0];
  const int*   ei     = (const int*)  d_in[1];
  const int*   srcp   = ei;
  const int*   dstp   = ei + NE;
  const int*   fl     = (const int*)  d_in[2];
  const float* W_emd  = (const float*)d_in[3];
  const float* b_emd  = (const float*)d_in[4];
  const float* W_aggr = (const float*)d_in[5];
  const float* b_aggr = (const float*)d_in[6];
  const float* w_ih   = (const float*)d_in[7];
  const float* w_hh   = (const float*)d_in[8];
  const float* b_ih   = (const float*)d_in[9];
  const float* b_hh   = (const float*)d_in[10];
  const float* W1     = (const float*)d_in[11];
  const float* b1     = (const float*)d_in[12];
  const float* W2     = (const float*)d_in[13];
  const float* b2     = (const float*)d_in[14];
  const float* W3     = (const float*)d_in[15];
  const float* b3     = (const float*)d_in[16];

  char* ws = (char*)d_ws;
  _Float16* h16   = (_Float16*)(ws + OFF_H);
  int*   cso      = (int*)  (ws + OFF_CSO);
  int*   deg      = (int*)  (ws + OFF_DEG);
  int*   cur      = (int*)  (ws + OFF_CUR);
  int*   csr_pack = (int*)  (ws + OFF_CSRC);
  int*   bsum     = (int*)  (ws + OFF_BSUM);
  int*   node_list= (int*)  (ws + OFF_NLIST);
  _Float16* Wch   = (_Float16*)(ws + OFF_WCH);
  float* ghc      = (float*)(ws + OFF_GHC);
  float* mb       = (float*)(ws + OFF_MB);
  _Float16* W1h   = (_Float16*)(ws + OFF_W1H);
  _Float16* W2h   = (_Float16*)(ws + OFF_W2H);
  int*   cnt      = (int*)  (ws + OFF_CNT);
  float* outp     = (float*)d_out;

  const int nsb = (NN + SCB - 1)/SCB;   // 196 scan blocks

  (void)hipMemsetAsync(ws + OFF_CNT, 0, 512, stream);
  (void)hipMemsetAsync(ws + OFF_DEG, 0, 1600000, stream);   // deg + cur
  k_pre<<<2048, 256, 0, stream>>>(h16, fl, dstp, W_emd, b_emd, cnt, deg);
  k_scan<<<1, 64, 0, stream>>>(cnt);
  k_fill_n<<<196, 256, 0, stream>>>(fl, cnt, node_list);
  k_cscan1<<<nsb, SCB, 0, stream>>>(deg, cso, bsum);
  k_cscan2_prep<<<256, 256, 0, stream>>>(bsum, cso, nsb,
                                  w_ih, W_aggr, b_aggr, w_hh, W_emd, b_emd, b_hh,
                                  W1, W2, Wch, ghc, mb, W1h, W2h);
  k_cscan3<<<nsb, SCB, 0, stream>>>(cso, bsum);
  k_csr_fill<<<1024, 256, 0, stream>>>(srcp, dstp, fl, cso, cur, csr_pack);
  for (int l = 1; l < NLVL; l++)
    k_level_one<<<512, 512, 0, stream>>>(cnt, l, node_list, cso, csr_pack, x,
                                         Wch, ghc, mb, w_ih, b_ih, W_emd, b_emd, h16);
  k_mlp_pw<<<256, 1024, 0, stream>>>(h16, W1h, b1, W2h, b2, W3, b3, outp);
}